// Round 4
// baseline (2785.548 us; speedup 1.0000x reference)
//
#include <hip/hip_runtime.h>

#define CH 256
#define KC 8192
#define NT 32768

#define TM 128         // tokens per block
#define TN 128         // codes per jt tile
#define BK 32          // channels staged per stage
#define YS 4           // code quarters (grid.y)
#define JQ (KC / YS)   // 2048 codes per block
#define NSTG ((JQ / TN) * (CH / BK))   // 16 jt * 8 c0 = 128 stages

typedef _Float16 half4_t __attribute__((ext_vector_type(4)));
typedef _Float16 half8_t __attribute__((ext_vector_type(8)));
typedef float floatx4 __attribute__((ext_vector_type(4)));

// XOR-swizzled LDS offset (halves) for row-major [row][BK] tiles, 16B chunks.
__device__ __forceinline__ int swz(int row, int chunk) {
    return row * BK + ((chunk ^ ((row >> 1) & 3)) << 3);
}

// ---------------------------------------------------------------------------
// Kernel 0: split embeddings fp32 -> (hi, lo) fp16 arrays
// ---------------------------------------------------------------------------
__global__ void k_split(const float* __restrict__ x,
                        _Float16* __restrict__ xh,
                        _Float16* __restrict__ xl) {
    int i = blockIdx.x * blockDim.x + threadIdx.x;
    float4 v = ((const float4*)x)[i];
    float va[4] = {v.x, v.y, v.z, v.w};
    half4_t h, l;
    #pragma unroll
    for (int q = 0; q < 4; ++q) {
        _Float16 hh = (_Float16)va[q];
        h[q] = hh;
        l[q] = (_Float16)(va[q] - (float)hh);
    }
    ((half4_t*)xh)[i] = h;
    ((half4_t*)xl)[i] = l;
}

// ---------------------------------------------------------------------------
// Kernel 1: codebook row = ces/clip(usage) -> fp16 hi/lo + cbsq.
// Also zero hist and init packed argmin keys.
// ---------------------------------------------------------------------------
__global__ void k_codebook(const float* __restrict__ usage,
                           const float* __restrict__ ces,
                           _Float16* __restrict__ cbh,
                           _Float16* __restrict__ cbl,
                           float* __restrict__ cbsq,
                           int* __restrict__ hist,
                           unsigned long long* __restrict__ packed) {
    int k = blockIdx.x;
    int c = threadIdx.x;
    float uc = fmaxf(usage[k], 1e-5f);
    float v  = ces[k * CH + c];
    float cb = v / uc;
    _Float16 h = (_Float16)cb;
    cbh[k * CH + c] = h;
    cbl[k * CH + c] = (_Float16)(cb - (float)h);

    float p = cb * cb;
    #pragma unroll
    for (int off = 32; off; off >>= 1) p += __shfl_down(p, off);
    __shared__ float ps[4];
    int lane = c & 63, w = c >> 6;
    if (lane == 0) ps[w] = p;
    __syncthreads();
    if (c == 0) cbsq[k] = ps[0] + ps[1] + ps[2] + ps[3];
    if (c == 1) hist[k] = 0;
    int gid = blockIdx.x * CH + c;
    if (gid < NT) packed[gid] = 0xFFFFFFFFFFFFFFFFull;
}

// ---------------------------------------------------------------------------
// Kernel 2: fp16-split MFMA argmin. Single LDS buffer + register prefetch,
// 2 barriers/stage (m97 structure), 32KB+2KB LDS -> 4 blocks/CU.
// Block: 128 tokens x 2048 codes (one quarter), 128 stages.
// ---------------------------------------------------------------------------
__launch_bounds__(256, 4)
__global__ void k_argmin(const _Float16* __restrict__ eh,
                         const _Float16* __restrict__ el,
                         const _Float16* __restrict__ cbh,
                         const _Float16* __restrict__ cbl,
                         const float* __restrict__ cbsq,
                         unsigned long long* __restrict__ packed) {
    __shared__ __align__(16) _Float16 sm[4][TM * BK];   // Ah, Al, Bh, Bl: 32 KiB
    __shared__ float cand_v[2][TM];
    __shared__ int   cand_i[2][TM];

    const int t    = threadIdx.x;
    const int lane = t & 63;
    const int wave = t >> 6;
    const int wx   = wave & 1;        // code half (64 codes)
    const int wy   = wave >> 1;       // token half (64 tokens)
    const int lr   = lane & 15;
    const int koq  = lane >> 4;       // k-chunk (quad) for fragments

    const int n0 = blockIdx.x * TM;
    const int jq = blockIdx.y * JQ;

    const int srow = t >> 1;          // staging row
    const int q0   = (t & 1) * 2;     // staging 16B-chunk base

    half8_t rAh[2], rAl[2], rBh[2], rBl[2];

    auto gload = [&](int s) {
        int c0 = (s & 7) * BK;
        int jb = jq + (s >> 3) * TN;
        size_t abase = (size_t)(n0 + srow) * CH + c0;
        size_t bbase = (size_t)(jb + srow) * CH + c0;
        #pragma unroll
        for (int i = 0; i < 2; ++i) {
            int kc = (q0 + i) * 8;
            rAh[i] = *(const half8_t*)(eh  + abase + kc);
            rAl[i] = *(const half8_t*)(el  + abase + kc);
            rBh[i] = *(const half8_t*)(cbh + bbase + kc);
            rBl[i] = *(const half8_t*)(cbl + bbase + kc);
        }
    };
    auto lstore = [&]() {
        #pragma unroll
        for (int i = 0; i < 2; ++i) {
            int off = swz(srow, q0 + i);
            *(half8_t*)&sm[0][off] = rAh[i];
            *(half8_t*)&sm[1][off] = rAl[i];
            *(half8_t*)&sm[2][off] = rBh[i];
            *(half8_t*)&sm[3][off] = rBl[i];
        }
    };

    float minv[16];
    int   mini[16];
    #pragma unroll
    for (int e = 0; e < 16; ++e) { minv[e] = 3.402823466e38f; mini[e] = 0; }

    floatx4 acc[4][4];
    #pragma unroll
    for (int mf = 0; mf < 4; ++mf)
        #pragma unroll
        for (int nf = 0; nf < 4; ++nf)
            acc[mf][nf] = (floatx4){0.f, 0.f, 0.f, 0.f};

    gload(0);

    #pragma unroll 1
    for (int s = 0; s < NSTG; ++s) {
        __syncthreads();              // all reads of stage s-1 complete
        lstore();                     // write stage s
        __syncthreads();              // stage s ready
        if (s + 1 < NSTG) gload(s + 1);   // prefetch (latency hidden by MFMAs)

        half8_t fah[4], fal[4];
        #pragma unroll
        for (int mf = 0; mf < 4; ++mf) {
            int off = swz(wy * 64 + mf * 16 + lr, koq);
            fah[mf] = *(const half8_t*)&sm[0][off];
            fal[mf] = *(const half8_t*)&sm[1][off];
        }
        #pragma unroll
        for (int nf = 0; nf < 4; ++nf) {
            int offb = swz(wx * 64 + nf * 16 + lr, koq);
            half8_t fbh = *(const half8_t*)&sm[2][offb];
            half8_t fbl = *(const half8_t*)&sm[3][offb];
            #pragma unroll
            for (int mf = 0; mf < 4; ++mf) {
                acc[mf][nf] = __builtin_amdgcn_mfma_f32_16x16x32_f16(
                    fah[mf], fbh, acc[mf][nf], 0, 0, 0);
                acc[mf][nf] = __builtin_amdgcn_mfma_f32_16x16x32_f16(
                    fah[mf], fbl, acc[mf][nf], 0, 0, 0);
                acc[mf][nf] = __builtin_amdgcn_mfma_f32_16x16x32_f16(
                    fal[mf], fbh, acc[mf][nf], 0, 0, 0);
            }
        }

        if ((s & 7) == 7) {           // end of a 128-code jt tile: fold
            int jbase = jq + (s >> 3) * TN;
            #pragma unroll
            for (int nf = 0; nf < 4; ++nf) {
                int j = jbase + wx * 64 + nf * 16 + lr;
                float sq = cbsq[j];
                #pragma unroll
                for (int mf = 0; mf < 4; ++mf) {
                    floatx4 a = acc[mf][nf];
                    #pragma unroll
                    for (int r = 0; r < 4; ++r) {
                        float sc = sq - 2.0f * a[r];
                        int e = mf * 4 + r;
                        if (sc < minv[e]) { minv[e] = sc; mini[e] = j; }
                    }
                    acc[mf][nf] = (floatx4){0.f, 0.f, 0.f, 0.f};
                }
            }
        }
    }

    __syncthreads();   // keep epilogue LDS writes after all fragment reads

    #pragma unroll
    for (int e = 0; e < 16; ++e) {
        float v = minv[e];
        int   x = mini[e];
        #pragma unroll
        for (int m = 1; m <= 8; m <<= 1) {
            float ov = __shfl_xor(v, m, 64);
            int   ox = __shfl_xor(x, m, 64);
            if (ov < v || (ov == v && ox < x)) { v = ov; x = ox; }
        }
        if (lr == 0) {
            int row = wy * 64 + (e >> 2) * 16 + (lane >> 4) * 4 + (e & 3);
            cand_v[wx][row] = v;
            cand_i[wx][row] = x;
        }
    }
    __syncthreads();

    if (t < TM) {
        float v0 = cand_v[0][t]; int i0 = cand_i[0][t];
        float v1 = cand_v[1][t]; int i1 = cand_i[1][t];
        if (v1 < v0 || (v1 == v0 && i1 < i0)) { v0 = v1; i0 = i1; }
        unsigned sb = __float_as_uint(v0);
        sb = (sb & 0x80000000u) ? ~sb : (sb | 0x80000000u);
        unsigned long long key = ((unsigned long long)sb << 32) | (unsigned)i0;
        atomicMin(&packed[n0 + t], key);
    }
}

// ---------------------------------------------------------------------------
// Kernel 3a: histogram of codes (int atomics, 8192 bins)
// ---------------------------------------------------------------------------
__global__ void k_hist(const unsigned long long* __restrict__ packed,
                       int* __restrict__ hist) {
    int n = blockIdx.x * 256 + threadIdx.x;
    int k = (int)(packed[n] & 0xFFFFFFFFull);
    atomicAdd(&hist[k], 1);
}

// ---------------------------------------------------------------------------
// Kernel 3b: exclusive prefix sum over hist -> offs, cursor (1 block)
// ---------------------------------------------------------------------------
__global__ void k_scan(const int* __restrict__ hist,
                       int* __restrict__ offs,
                       int* __restrict__ cursor) {
    __shared__ int bs[256];
    int t = threadIdx.x;
    int base = t * 32;
    int loc[32];
    int s = 0;
    #pragma unroll
    for (int i = 0; i < 32; ++i) { loc[i] = s; s += hist[base + i]; }
    int mysum = s;
    bs[t] = s;
    __syncthreads();
    for (int off = 1; off < 256; off <<= 1) {
        int v = (t >= off) ? bs[t - off] : 0;
        __syncthreads();
        bs[t] += v;
        __syncthreads();
    }
    int excl = bs[t] - mysum;
    #pragma unroll
    for (int i = 0; i < 32; ++i) {
        int o = excl + loc[i];
        offs[base + i]   = o;
        cursor[base + i] = o;
    }
}

// ---------------------------------------------------------------------------
// Kernel 3c: scatter token ids into code-sorted buckets
// ---------------------------------------------------------------------------
__global__ void k_scatter(const unsigned long long* __restrict__ packed,
                          int* __restrict__ cursor,
                          int* __restrict__ bucket) {
    int n = blockIdx.x * 256 + threadIdx.x;
    int k = (int)(packed[n] & 0xFFFFFFFFull);
    int pos = atomicAdd(&cursor[k], 1);
    bucket[pos] = n;
}

// ---------------------------------------------------------------------------
// Kernel 3d: per-code EMA update (one wave per code, no atomics)
// ---------------------------------------------------------------------------
__global__ void k_ema(const float* __restrict__ emb,
                      const float* __restrict__ ces,
                      const float* __restrict__ usage,
                      const int* __restrict__ hist,
                      const int* __restrict__ offs,
                      const int* __restrict__ bucket,
                      float* __restrict__ out_ces,
                      float* __restrict__ out_usage) {
    const float s = 0.01f;
    const float oms = 1.0f - s;
    int t = threadIdx.x, wave = t >> 6, lane = t & 63;
    int k = blockIdx.x * 4 + wave;
    int start = offs[k], cnt = hist[k];
    float a0 = 0.f, a1 = 0.f, a2 = 0.f, a3 = 0.f;
    for (int i = 0; i < cnt; ++i) {
        int n = bucket[start + i];
        float4 v = *(const float4*)&emb[(size_t)n * CH + lane * 4];
        a0 += v.x; a1 += v.y; a2 += v.z; a3 += v.w;
    }
    float4 o = *(const float4*)&ces[(size_t)k * CH + lane * 4];
    float4 r = {oms * o.x + s * a0, oms * o.y + s * a1,
                oms * o.z + s * a2, oms * o.w + s * a3};
    *(float4*)&out_ces[(size_t)k * CH + lane * 4] = r;
    if (lane == 0) out_usage[k] = oms * usage[k] + s * (float)cnt;
}

// ---------------------------------------------------------------------------
// Kernel 4: gather + straight-through + loss partials (pure streaming)
// ---------------------------------------------------------------------------
__global__ void k_gather(const float* __restrict__ emb,
                         const float* __restrict__ ces,
                         const float* __restrict__ usage,
                         const unsigned long long* __restrict__ packed,
                         float* __restrict__ out_eq,
                         float* __restrict__ codes_f,
                         float* __restrict__ partials) {
    int t = threadIdx.x;
    int wave = t >> 6, lane = t & 63;
    int n = blockIdx.x * 4 + wave;
    int k = (int)(packed[n] & 0xFFFFFFFFull);
    float uc = fmaxf(usage[k], 1e-5f);
    int c = lane * 4;

    float4 e = *(const float4*)&emb[(size_t)n * CH + c];
    float4 v = *(const float4*)&ces[(size_t)k * CH + c];
    float ea[4] = {e.x, e.y, e.z, e.w};
    float va[4] = {v.x, v.y, v.z, v.w};
    float eqa[4];
    float p = 0.0f;
    #pragma unroll
    for (int q = 0; q < 4; ++q) {
        float cb = va[q] / uc;
        float eq = ea[q] + (cb - ea[q]);
        eqa[q] = eq;
        float d = eq - ea[q];
        p += d * d;
    }
    *(float4*)&out_eq[(size_t)n * CH + c] =
        (float4){eqa[0], eqa[1], eqa[2], eqa[3]};

    #pragma unroll
    for (int off = 32; off; off >>= 1) p += __shfl_down(p, off);
    __shared__ float ps[4];
    if (lane == 0) {
        ps[wave] = p;
        codes_f[n] = (float)k;
    }
    __syncthreads();
    if (t == 0) partials[blockIdx.x] = ps[0] + ps[1] + ps[2] + ps[3];
}

// ---------------------------------------------------------------------------
// Kernel 5: reduce loss partials (8192 floats), mean over 2^23 elements
// ---------------------------------------------------------------------------
__global__ void k_final(const float* __restrict__ partials,
                        float* __restrict__ out_loss) {
    int t = threadIdx.x;
    float p = 0.0f;
    for (int i = t; i < NT / 4; i += 256) p += partials[i];
    #pragma unroll
    for (int off = 32; off; off >>= 1) p += __shfl_down(p, off);
    __shared__ float ps[4];
    if ((t & 63) == 0) ps[t >> 6] = p;
    __syncthreads();
    if (t == 0)
        out_loss[0] = (ps[0] + ps[1] + ps[2] + ps[3]) * (1.0f / 8388608.0f);
}

extern "C" void kernel_launch(void* const* d_in, const int* in_sizes, int n_in,
                              void* d_out, int out_size, void* d_ws, size_t ws_size,
                              hipStream_t stream) {
    const float* emb   = (const float*)d_in[0];  // [32768, 256]
    const float* usage = (const float*)d_in[1];  // [8192]
    const float* ces   = (const float*)d_in[2];  // [8192, 256]

    float* out      = (float*)d_out;
    float* o_codes  = out;                       // 32768
    float* o_eq     = out + NT;                  // 8388608
    float* o_loss   = o_eq + (size_t)NT * CH;    // 1
    float* o_usage  = o_loss + 1;                // 8192
    float* o_ces    = o_usage + KC;              // 2097152

    unsigned long long* packed = (unsigned long long*)d_ws;   // NT u64
    float* cbsq     = (float*)(packed + NT);                  // KC
    float* partials = cbsq + KC;                              // NT/4
    int* hist   = (int*)(partials + NT / 4);                  // KC
    int* offs   = hist + KC;                                  // KC
    int* cursor = offs + KC;                                  // KC
    int* bucket = cursor + KC;                                // NT
    _Float16* eh  = (_Float16*)(bucket + NT);                 // NT*CH
    _Float16* el  = eh + (size_t)NT * CH;
    _Float16* cbh = el + (size_t)NT * CH;                     // KC*CH
    _Float16* cbl = cbh + (size_t)KC * CH;

    k_split<<<NT * CH / 1024, 256, 0, stream>>>(emb, eh, el);
    k_codebook<<<KC, CH, 0, stream>>>(usage, ces, cbh, cbl, cbsq, hist, packed);
    dim3 agrid(NT / TM, YS);
    k_argmin<<<agrid, 256, 0, stream>>>(eh, el, cbh, cbl, cbsq, packed);
    k_hist<<<NT / 256, 256, 0, stream>>>(packed, hist);
    k_scan<<<1, 256, 0, stream>>>(hist, offs, cursor);
    k_scatter<<<NT / 256, 256, 0, stream>>>(packed, cursor, bucket);
    k_ema<<<KC / 4, 256, 0, stream>>>(emb, ces, usage, hist, offs, bucket,
                                      o_ces, o_usage);
    k_gather<<<NT / 4, 256, 0, stream>>>(emb, ces, usage, packed, o_eq,
                                         o_codes, partials);
    k_final<<<1, 256, 0, stream>>>(partials, o_loss);
}

// Round 5
// 646.636 us; speedup vs baseline: 4.3078x; 4.3078x over previous
//
#include <hip/hip_runtime.h>

#define CH 256
#define KC 8192
#define KCP 8448       // padded codebook: 3 * 2816, grid.y = 3
#define NT 32768

#define TM 128         // tokens per block
#define TN 128         // codes per jt tile
#define BK 32          // channels staged per stage
#define YS 3           // code thirds (grid.y)
#define JQ (KCP / YS)  // 2816 codes per block
#define NSTG ((JQ / TN) * (CH / BK))   // 22 jt * 8 c0 = 176 stages

typedef _Float16 half4_t __attribute__((ext_vector_type(4)));
typedef _Float16 half8_t __attribute__((ext_vector_type(8)));
typedef float floatx4 __attribute__((ext_vector_type(4)));

typedef __attribute__((address_space(1))) const unsigned int guint_t;
typedef __attribute__((address_space(3))) unsigned int luint_t;

// XOR-swizzled LDS offset (halves) for row-major [row][BK] tiles, 16B chunks.
__device__ __forceinline__ int swz(int row, int chunk) {
    return row * BK + ((chunk ^ ((row >> 1) & 3)) << 3);
}

// ---------------------------------------------------------------------------
// Kernel 1 (fused prep):
//  blocks [0, KCP):   codebook row -> fp16 hi/lo + cbsq (pad rows: 0 / 3e38),
//                     zero hist, init packed keys
//  blocks [KCP, ...): split embeddings fp32 -> fp16 hi/lo (1 float4/thread)
// ---------------------------------------------------------------------------
__global__ void k_prep(const float* __restrict__ usage,
                       const float* __restrict__ ces,
                       const float* __restrict__ emb,
                       _Float16* __restrict__ cbh,
                       _Float16* __restrict__ cbl,
                       float* __restrict__ cbsq,
                       _Float16* __restrict__ eh,
                       _Float16* __restrict__ el,
                       int* __restrict__ hist,
                       unsigned long long* __restrict__ packed) {
    int b = blockIdx.x, t = threadIdx.x;
    if (b < KCP) {
        if (b < KC) {
            float uc = fmaxf(usage[b], 1e-5f);
            float v  = ces[b * CH + t];
            float cb = v / uc;
            _Float16 h = (_Float16)cb;
            cbh[b * CH + t] = h;
            cbl[b * CH + t] = (_Float16)(cb - (float)h);

            float p = cb * cb;
            #pragma unroll
            for (int off = 32; off; off >>= 1) p += __shfl_down(p, off);
            __shared__ float ps[4];
            int lane = t & 63, w = t >> 6;
            if (lane == 0) ps[w] = p;
            __syncthreads();
            if (t == 0) cbsq[b] = ps[0] + ps[1] + ps[2] + ps[3];
            if (t == 1) hist[b] = 0;
            int gid = b * CH + t;
            if (gid < NT) packed[gid] = 0xFFFFFFFFFFFFFFFFull;
        } else {
            cbh[b * CH + t] = (_Float16)0.0f;
            cbl[b * CH + t] = (_Float16)0.0f;
            if (t == 0) cbsq[b] = 3.0e38f;
        }
    } else {
        int i = (b - KCP) * 256 + t;     // float4 index
        float4 v = ((const float4*)emb)[i];
        float va[4] = {v.x, v.y, v.z, v.w};
        half4_t h, l;
        #pragma unroll
        for (int q = 0; q < 4; ++q) {
            _Float16 hh = (_Float16)va[q];
            h[q] = hh;
            l[q] = (_Float16)(va[q] - (float)hh);
        }
        ((half4_t*)eh)[i] = h;
        ((half4_t*)el)[i] = l;
    }
}

// ---------------------------------------------------------------------------
// Kernel 2: fp16-split MFMA argmin.
// Single 32KB LDS buffer staged by global_load_lds (16B DMA, no staging
// VGPRs, no ds_write). Wave w DMAs array w of {Ah,Al,Bh,Bl}; lane->chunk
// assignment pre-applies the XOR swizzle so fragment reads stay conflict-free.
// Block: 128 tokens x 2816 codes (one third, padded), 176 stages.
// ---------------------------------------------------------------------------
__launch_bounds__(256, 3)
__global__ void k_argmin(const _Float16* __restrict__ eh,
                         const _Float16* __restrict__ el,
                         const _Float16* __restrict__ cbh,
                         const _Float16* __restrict__ cbl,
                         const float* __restrict__ cbsq,
                         unsigned long long* __restrict__ packed) {
    __shared__ __align__(16) _Float16 sm[4][TM * BK];   // 32 KiB
    __shared__ float cand_v[2][TM];
    __shared__ int   cand_i[2][TM];

    const int t    = threadIdx.x;
    const int lane = t & 63;
    const int wave = t >> 6;
    const int wx   = wave & 1;        // code half (64 codes)
    const int wy   = wave >> 1;       // token half (64 tokens)
    const int lr   = lane & 15;
    const int koq  = lane >> 4;       // k-chunk (quad) for fragments

    const int n0 = blockIdx.x * TM;
    const int jq = blockIdx.y * JQ;

    // DMA assignment: wave w stages array w. Per-lane source chunk applies
    // the inverse swizzle: q = (lane&3) ^ ((lane>>3)&3)  (i*16 doesn't affect
    // (row>>1)&3 since 8 | i*8). Row within issue i: r = i*16 + (lane>>2).
    const _Float16* dsrc = (wave == 0) ? eh : (wave == 1) ? el
                         : (wave == 2) ? cbh : cbl;
    const int qsw   = (lane & 3) ^ ((lane >> 3) & 3);
    const int lrow  = lane >> 2;

    float minv[16];
    int   mini[16];
    #pragma unroll
    for (int e = 0; e < 16; ++e) { minv[e] = 3.402823466e38f; mini[e] = 0; }

    floatx4 acc[4][4];
    #pragma unroll
    for (int mf = 0; mf < 4; ++mf)
        #pragma unroll
        for (int nf = 0; nf < 4; ++nf)
            acc[mf][nf] = (floatx4){0.f, 0.f, 0.f, 0.f};

    #pragma unroll 1
    for (int s = 0; s < NSTG; ++s) {
        const int c0 = (s & 7) * BK;
        const int jb = jq + (s >> 3) * TN;
        const int rb = (wave < 2) ? n0 : jb;

        // ---- DMA stage s into LDS (8 x 1KB per wave) ----
        {
            const _Float16* gbase = dsrc + (size_t)(rb + lrow) * CH + c0 + qsw * 8;
            #pragma unroll
            for (int i = 0; i < 8; ++i) {
                const _Float16* g = gbase + (size_t)(i * 16) * CH;
                __builtin_amdgcn_global_load_lds(
                    (guint_t*)g, (luint_t*)&sm[wave][i * 512], 16, 0, 0);
            }
        }
        __syncthreads();   // drains vmcnt: stage s visible to all waves

        // ---- fragments + MFMA ----
        half8_t fah[4], fal[4];
        #pragma unroll
        for (int mf = 0; mf < 4; ++mf) {
            int off = swz(wy * 64 + mf * 16 + lr, koq);
            fah[mf] = *(const half8_t*)&sm[0][off];
            fal[mf] = *(const half8_t*)&sm[1][off];
        }
        #pragma unroll
        for (int nf = 0; nf < 4; ++nf) {
            int offb = swz(wx * 64 + nf * 16 + lr, koq);
            half8_t fbh = *(const half8_t*)&sm[2][offb];
            half8_t fbl = *(const half8_t*)&sm[3][offb];
            #pragma unroll
            for (int mf = 0; mf < 4; ++mf) {
                acc[mf][nf] = __builtin_amdgcn_mfma_f32_16x16x32_f16(
                    fah[mf], fbh, acc[mf][nf], 0, 0, 0);
                acc[mf][nf] = __builtin_amdgcn_mfma_f32_16x16x32_f16(
                    fah[mf], fbl, acc[mf][nf], 0, 0, 0);
                acc[mf][nf] = __builtin_amdgcn_mfma_f32_16x16x32_f16(
                    fal[mf], fbh, acc[mf][nf], 0, 0, 0);
            }
        }

        if ((s & 7) == 7) {           // end of a 128-code jt tile: fold
            int jbase = jq + (s >> 3) * TN;
            #pragma unroll
            for (int nf = 0; nf < 4; ++nf) {
                int j = jbase + wx * 64 + nf * 16 + lr;
                float sq = cbsq[j];
                #pragma unroll
                for (int mf = 0; mf < 4; ++mf) {
                    floatx4 a = acc[mf][nf];
                    #pragma unroll
                    for (int r = 0; r < 4; ++r) {
                        float sc = sq - 2.0f * a[r];
                        int e = mf * 4 + r;
                        if (sc < minv[e]) { minv[e] = sc; mini[e] = j; }
                    }
                    acc[mf][nf] = (floatx4){0.f, 0.f, 0.f, 0.f};
                }
            }
        }
        __syncthreads();   // all LDS reads done before next stage's DMA
    }

    // ---- epilogue: cross-lane then cross-wave argmin reduce ----
    #pragma unroll
    for (int e = 0; e < 16; ++e) {
        float v = minv[e];
        int   x = mini[e];
        #pragma unroll
        for (int m = 1; m <= 8; m <<= 1) {
            float ov = __shfl_xor(v, m, 64);
            int   ox = __shfl_xor(x, m, 64);
            if (ov < v || (ov == v && ox < x)) { v = ov; x = ox; }
        }
        if (lr == 0) {
            int row = wy * 64 + (e >> 2) * 16 + (lane >> 4) * 4 + (e & 3);
            cand_v[wx][row] = v;
            cand_i[wx][row] = x;
        }
    }
    __syncthreads();

    if (t < TM) {
        float v0 = cand_v[0][t]; int i0 = cand_i[0][t];
        float v1 = cand_v[1][t]; int i1 = cand_i[1][t];
        if (v1 < v0 || (v1 == v0 && i1 < i0)) { v0 = v1; i0 = i1; }
        unsigned sb = __float_as_uint(v0);
        sb = (sb & 0x80000000u) ? ~sb : (sb | 0x80000000u);
        unsigned long long key = ((unsigned long long)sb << 32) | (unsigned)i0;
        atomicMin(&packed[n0 + t], key);
    }
}

// ---------------------------------------------------------------------------
// Kernel 3: gather + straight-through + loss partials + histogram
// ---------------------------------------------------------------------------
__global__ void k_gather(const float* __restrict__ emb,
                         const float* __restrict__ ces,
                         const float* __restrict__ usage,
                         const unsigned long long* __restrict__ packed,
                         float* __restrict__ out_eq,
                         float* __restrict__ codes_f,
                         int* __restrict__ hist,
                         float* __restrict__ partials) {
    int t = threadIdx.x;
    int wave = t >> 6, lane = t & 63;
    int n = blockIdx.x * 4 + wave;
    int k = (int)(packed[n] & 0xFFFFFFFFull);
    float uc = fmaxf(usage[k], 1e-5f);
    int c = lane * 4;

    float4 e = *(const float4*)&emb[(size_t)n * CH + c];
    float4 v = *(const float4*)&ces[(size_t)k * CH + c];
    float ea[4] = {e.x, e.y, e.z, e.w};
    float va[4] = {v.x, v.y, v.z, v.w};
    float eqa[4];
    float p = 0.0f;
    #pragma unroll
    for (int q = 0; q < 4; ++q) {
        float cb = va[q] / uc;
        float eq = ea[q] + (cb - ea[q]);
        eqa[q] = eq;
        float d = eq - ea[q];
        p += d * d;
    }
    *(float4*)&out_eq[(size_t)n * CH + c] =
        (float4){eqa[0], eqa[1], eqa[2], eqa[3]};

    #pragma unroll
    for (int off = 32; off; off >>= 1) p += __shfl_down(p, off);
    __shared__ float ps[4];
    if (lane == 0) {
        ps[wave] = p;
        codes_f[n] = (float)k;
        atomicAdd(&hist[k], 1);
    }
    __syncthreads();
    if (t == 0) partials[blockIdx.x] = ps[0] + ps[1] + ps[2] + ps[3];
}

// ---------------------------------------------------------------------------
// Kernel 4: exclusive prefix sum over hist -> offs, cursor (1 block)
// ---------------------------------------------------------------------------
__global__ void k_scan(const int* __restrict__ hist,
                       int* __restrict__ offs,
                       int* __restrict__ cursor) {
    __shared__ int bs[256];
    int t = threadIdx.x;
    int base = t * 32;
    int loc[32];
    int s = 0;
    #pragma unroll
    for (int i = 0; i < 32; ++i) { loc[i] = s; s += hist[base + i]; }
    int mysum = s;
    bs[t] = s;
    __syncthreads();
    for (int off = 1; off < 256; off <<= 1) {
        int v = (t >= off) ? bs[t - off] : 0;
        __syncthreads();
        bs[t] += v;
        __syncthreads();
    }
    int excl = bs[t] - mysum;
    #pragma unroll
    for (int i = 0; i < 32; ++i) {
        int o = excl + loc[i];
        offs[base + i]   = o;
        cursor[base + i] = o;
    }
}

// ---------------------------------------------------------------------------
// Kernel 5: scatter token ids into code-sorted buckets
// ---------------------------------------------------------------------------
__global__ void k_scatter(const unsigned long long* __restrict__ packed,
                          int* __restrict__ cursor,
                          int* __restrict__ bucket) {
    int n = blockIdx.x * 256 + threadIdx.x;
    int k = (int)(packed[n] & 0xFFFFFFFFull);
    int pos = atomicAdd(&cursor[k], 1);
    bucket[pos] = n;
}

// ---------------------------------------------------------------------------
// Kernel 6: per-code EMA (one BLOCK per code: coalesced 1KB row loads,
// thread t owns channel t, no atomics, no wave-serial latency chain)
// ---------------------------------------------------------------------------
__global__ void k_ema(const float* __restrict__ emb,
                      const float* __restrict__ ces,
                      const float* __restrict__ usage,
                      const int* __restrict__ hist,
                      const int* __restrict__ offs,
                      const int* __restrict__ bucket,
                      float* __restrict__ out_ces,
                      float* __restrict__ out_usage) {
    const float s = 0.01f;
    const float oms = 1.0f - s;
    int k = blockIdx.x, t = threadIdx.x;
    int start = offs[k], cnt = hist[k];
    float sum = 0.0f;
    #pragma unroll 2
    for (int i = 0; i < cnt; ++i) {
        int n = bucket[start + i];            // block-uniform (scalar) load
        sum += emb[(size_t)n * CH + t];       // coalesced row
    }
    out_ces[(size_t)k * CH + t] = oms * ces[(size_t)k * CH + t] + s * sum;
    if (t == 0) out_usage[k] = oms * usage[k] + s * (float)cnt;
}

// ---------------------------------------------------------------------------
// Kernel 7: reduce loss partials, mean over 2^23 elements
// ---------------------------------------------------------------------------
__global__ void k_final(const float* __restrict__ partials,
                        float* __restrict__ out_loss) {
    int t = threadIdx.x;
    float p = 0.0f;
    for (int i = t; i < NT / 4; i += 256) p += partials[i];
    #pragma unroll
    for (int off = 32; off; off >>= 1) p += __shfl_down(p, off);
    __shared__ float ps[4];
    if ((t & 63) == 0) ps[t >> 6] = p;
    __syncthreads();
    if (t == 0)
        out_loss[0] = (ps[0] + ps[1] + ps[2] + ps[3]) * (1.0f / 8388608.0f);
}

extern "C" void kernel_launch(void* const* d_in, const int* in_sizes, int n_in,
                              void* d_out, int out_size, void* d_ws, size_t ws_size,
                              hipStream_t stream) {
    const float* emb   = (const float*)d_in[0];  // [32768, 256]
    const float* usage = (const float*)d_in[1];  // [8192]
    const float* ces   = (const float*)d_in[2];  // [8192, 256]

    float* out      = (float*)d_out;
    float* o_codes  = out;                       // 32768
    float* o_eq     = out + NT;                  // 8388608
    float* o_loss   = o_eq + (size_t)NT * CH;    // 1
    float* o_usage  = o_loss + 1;                // 8192
    float* o_ces    = o_usage + KC;              // 2097152

    unsigned long long* packed = (unsigned long long*)d_ws;   // NT u64
    float* cbsq     = (float*)(packed + NT);                  // KCP
    float* partials = cbsq + KCP;                             // NT/4
    int* hist   = (int*)(partials + NT / 4);                  // KC
    int* offs   = hist + KC;                                  // KC
    int* cursor = offs + KC;                                  // KC
    int* bucket = cursor + KC;                                // NT
    _Float16* eh  = (_Float16*)(bucket + NT);                 // NT*CH
    _Float16* el  = eh + (size_t)NT * CH;
    _Float16* cbh = el + (size_t)NT * CH;                     // KCP*CH
    _Float16* cbl = cbh + (size_t)KCP * CH;

    k_prep<<<KCP + NT * CH / 1024, 256, 0, stream>>>(
        usage, ces, emb, cbh, cbl, cbsq, eh, el, hist, packed);
    dim3 agrid(NT / TM, YS);
    k_argmin<<<agrid, 256, 0, stream>>>(eh, el, cbh, cbl, cbsq, packed);
    k_gather<<<NT / 4, 256, 0, stream>>>(emb, ces, usage, packed, o_eq,
                                         o_codes, hist, partials);
    k_scan<<<1, 256, 0, stream>>>(hist, offs, cursor);
    k_scatter<<<NT / 256, 256, 0, stream>>>(packed, cursor, bucket);
    k_ema<<<KC, 256, 0, stream>>>(emb, ces, usage, hist, offs, bucket,
                                  o_ces, o_usage);
    k_final<<<1, 256, 0, stream>>>(partials, o_loss);
}